// Round 6
// baseline (334.192 us; speedup 1.0000x reference)
//
#include <hip/hip_runtime.h>

namespace {
constexpr int Bn = 8, Cn = 256, Kn = 128, Hn = 112, Wn = 112;
constexpr int Pn = Hn * Wn;                       // 12544
constexpr long long NOUT = (long long)Bn * Kn * Pn;  // 12845056 per output tensor
}

// lcT[c*128 + k] = lc[k*256 + c]  (tiny: 32768 elements)
__global__ __launch_bounds__(256) void transpose_lc(const float* __restrict__ lc,
                                                    float* __restrict__ lcT) {
  int i = blockIdx.x * 256 + threadIdx.x;
  int c = i >> 7, k = i & 127;
  lcT[i] = lc[k * Cn + c];
}

// comb[b][k][p] = sum_c linComb[k][c] * x[b][c][p]
// block = 256 threads; tile = K(128 full) x P(128); thread owns 16 k x 4 p.
__global__ __launch_bounds__(256) void gemm_comb(const float* __restrict__ x,
                                                 const float* __restrict__ lcT,
                                                 float* __restrict__ comb) {
  __shared__ __align__(16) float xs[8][128];
  __shared__ __align__(16) float ls[8][128];
  const int tid = threadIdx.x;
  const int b = blockIdx.x / 98;
  const int pbase = (blockIdx.x % 98) * 128;
  const int kbase = (tid >> 5) * 16;   // 8 k-groups of 16
  const int ploc = (tid & 31) * 4;     // 32 pixel-groups of 4

  // staging coords: one float4 of x and one of lcT per thread per chunk
  const int s_cc = tid >> 5;           // 0..7
  const int s_e4 = (tid & 31) * 4;     // 0..124

  float acc[16][4];
#pragma unroll
  for (int i = 0; i < 16; ++i)
#pragma unroll
    for (int j = 0; j < 4; ++j) acc[i][j] = 0.f;

  const float* xb = x + (size_t)b * Cn * Pn + pbase;

  for (int cb = 0; cb < Cn; cb += 8) {
    float4 xv4 = *reinterpret_cast<const float4*>(&xb[(size_t)(cb + s_cc) * Pn + s_e4]);
    float4 lv4 = *reinterpret_cast<const float4*>(&lcT[(cb + s_cc) * Kn + s_e4]);
    *reinterpret_cast<float4*>(&xs[s_cc][s_e4]) = xv4;
    *reinterpret_cast<float4*>(&ls[s_cc][s_e4]) = lv4;
    __syncthreads();
#pragma unroll
    for (int cc = 0; cc < 8; ++cc) {
      float4 xv = *reinterpret_cast<const float4*>(&xs[cc][ploc]);
      float xa[4] = {xv.x, xv.y, xv.z, xv.w};
#pragma unroll
      for (int i4 = 0; i4 < 4; ++i4) {
        float4 lv = *reinterpret_cast<const float4*>(&ls[cc][kbase + i4 * 4]);
        float la[4] = {lv.x, lv.y, lv.z, lv.w};
#pragma unroll
        for (int ii = 0; ii < 4; ++ii) {
          const int i = i4 * 4 + ii;
#pragma unroll
          for (int j = 0; j < 4; ++j) acc[i][j] += la[ii] * xa[j];
        }
      }
    }
    __syncthreads();
  }

  float* co = comb + (size_t)b * Kn * Pn + pbase + ploc;
#pragma unroll
  for (int i = 0; i < 16; ++i) {
    float4 v = make_float4(acc[i][0], acc[i][1], acc[i][2], acc[i][3]);
    *reinterpret_cast<float4*>(&co[(size_t)(kbase + i) * Pn]) = v;
  }
}

// One thread per (k, p): grid/weights computed once, reused across batch.
// box is batch-invariant (bilinear sample of ones = sum of valid weights).
template <int FUSE>
__global__ __launch_bounds__(256) void sample_all(const float* __restrict__ comb,
                                                  const float* __restrict__ geo,
                                                  const float* __restrict__ boxp,
                                                  float* __restrict__ outF,
                                                  float* __restrict__ outW,
                                                  float* __restrict__ outB) {
  const int k = blockIdx.y;
  const int p = blockIdx.x * 256 + threadIdx.x;  // 49*256 == 12544 exactly
  const int h = p / Wn;
  const int w = p - h * Wn;
  const float xn = (2.f * w + 1.f) / (float)Wn - 1.f;  // match ref's /Wn exactly
  const float yn = (2.f * h + 1.f) / (float)Hn - 1.f;

  const float* g = geo + k * 6;
  const float* t = boxp + k * 6;

  // geo sample: coords, weights, validity (align_corners=False, zeros pad)
  float ix = ((g[0] * xn + g[1] * yn + g[2] + 1.f) * Wn - 1.f) * 0.5f;
  float iy = ((g[3] * xn + g[4] * yn + g[5] + 1.f) * Hn - 1.f) * 0.5f;
  float x0f = floorf(ix), y0f = floorf(iy);
  float wx1 = ix - x0f, wx0 = 1.f - wx1;
  float wy1 = iy - y0f, wy0 = 1.f - wy1;
  float vx0 = (x0f >= 0.f && x0f <= (float)(Wn - 1)) ? 1.f : 0.f;
  float vx1 = (x0f + 1.f >= 0.f && x0f + 1.f <= (float)(Wn - 1)) ? 1.f : 0.f;
  float vy0 = (y0f >= 0.f && y0f <= (float)(Hn - 1)) ? 1.f : 0.f;
  float vy1 = (y0f + 1.f >= 0.f && y0f + 1.f <= (float)(Hn - 1)) ? 1.f : 0.f;
  int x0i = (int)fminf(fmaxf(x0f, 0.f), (float)(Wn - 1));
  int x1i = (int)fminf(fmaxf(x0f + 1.f, 0.f), (float)(Wn - 1));
  int y0i = (int)fminf(fmaxf(y0f, 0.f), (float)(Hn - 1));
  int y1i = (int)fminf(fmaxf(y0f + 1.f, 0.f), (float)(Hn - 1));
  float w00 = wx0 * wy0 * vx0 * vy0;
  float w01 = wx1 * wy0 * vx1 * vy0;
  float w10 = wx0 * wy1 * vx0 * vy1;
  float w11 = wx1 * wy1 * vx1 * vy1;
  int i00 = y0i * Wn + x0i, i01 = y0i * Wn + x1i;
  int i10 = y1i * Wn + x0i, i11 = y1i * Wn + x1i;

  // box value: same math on boxParams, image == ones -> no loads
  float bix = ((t[0] * xn + t[1] * yn + t[2] + 1.f) * Wn - 1.f) * 0.5f;
  float biy = ((t[3] * xn + t[4] * yn + t[5] + 1.f) * Hn - 1.f) * 0.5f;
  float bx0 = floorf(bix), by0 = floorf(biy);
  float bwx1 = bix - bx0, bwx0 = 1.f - bwx1;
  float bwy1 = biy - by0, bwy0 = 1.f - bwy1;
  float bvx0 = (bx0 >= 0.f && bx0 <= (float)(Wn - 1)) ? 1.f : 0.f;
  float bvx1 = (bx0 + 1.f >= 0.f && bx0 + 1.f <= (float)(Wn - 1)) ? 1.f : 0.f;
  float bvy0 = (by0 >= 0.f && by0 <= (float)(Hn - 1)) ? 1.f : 0.f;
  float bvy1 = (by0 + 1.f >= 0.f && by0 + 1.f <= (float)(Hn - 1)) ? 1.f : 0.f;
  float bv = bwx0 * bwy0 * bvx0 * bvy0 + bwx1 * bwy0 * bvx1 * bvy0 +
             bwx0 * bwy1 * bvx0 * bvy1 + bwx1 * bwy1 * bvx1 * bvy1;

#pragma unroll
  for (int b = 0; b < Bn; ++b) {
    const float* cp = comb + ((size_t)b * Kn + k) * Pn;
    float v = w00 * cp[i00] + w01 * cp[i01] + w10 * cp[i10] + w11 * cp[i11];
    size_t o = ((size_t)b * Kn + k) * Pn + p;
    outW[o] = v;
    outB[o] = bv;
    if (FUSE) outF[o] = v * bv;
  }
}

// finalPred = warped * box (only used when comb borrowed the finalPred region)
__global__ __launch_bounds__(256) void mul_fw(const float* __restrict__ w,
                                              const float* __restrict__ bx,
                                              float* __restrict__ f) {
  const long long n4 = NOUT / 4;
  for (long long i = blockIdx.x * 256LL + threadIdx.x; i < n4;
       i += (long long)gridDim.x * 256LL) {
    float4 a = reinterpret_cast<const float4*>(w)[i];
    float4 b = reinterpret_cast<const float4*>(bx)[i];
    reinterpret_cast<float4*>(f)[i] = make_float4(a.x * b.x, a.y * b.y, a.z * b.z, a.w * b.w);
  }
}

extern "C" void kernel_launch(void* const* d_in, const int* in_sizes, int n_in,
                              void* d_out, int out_size, void* d_ws, size_t ws_size,
                              hipStream_t stream) {
  (void)in_sizes; (void)n_in; (void)out_size;
  const float* x = (const float*)d_in[0];
  const float* lc = (const float*)d_in[1];
  const float* geo = (const float*)d_in[2];
  const float* boxp = (const float*)d_in[3];
  float* outF = (float*)d_out;
  float* outW = outF + NOUT;
  float* outB = outW + NOUT;

  const size_t comb_bytes = (size_t)NOUT * sizeof(float);
  const bool use_ws = ws_size >= comb_bytes;
  float* comb = use_ws ? (float*)d_ws : outF;  // fall back: borrow finalPred region
  float* lcT = outB;  // borrow box region for transposed linComb (box written later)

  transpose_lc<<<(Kn * Cn) / 256, 256, 0, stream>>>(lc, lcT);
  gemm_comb<<<Bn * (Pn / 128), 256, 0, stream>>>(x, lcT, comb);
  if (use_ws) {
    sample_all<1><<<dim3(Pn / 256, Kn), 256, 0, stream>>>(comb, geo, boxp, outF, outW, outB);
  } else {
    sample_all<0><<<dim3(Pn / 256, Kn), 256, 0, stream>>>(comb, geo, boxp, outF, outW, outB);
    mul_fw<<<2048, 256, 0, stream>>>(outW, outB, outF);
  }
}

// Round 9
// 308.362 us; speedup vs baseline: 1.0838x; 1.0838x over previous
//
#include <hip/hip_runtime.h>
#include <hip/hip_bf16.h>

namespace {
constexpr int Bn = 8, Cn = 256, Kn = 128, Hn = 112, Wn = 112;
constexpr int Pn = Hn * Wn;                          // 12544 = 98*128 = 49*256
constexpr long long NOUT = (long long)Bn * Kn * Pn;  // 12845056 per output tensor

typedef __attribute__((ext_vector_type(8))) short bf16x8;
typedef __attribute__((ext_vector_type(4))) float f32x4;

__device__ inline unsigned short f2bf(float f) {
  __hip_bfloat16 h = __float2bfloat16(f);  // RNE
  return __builtin_bit_cast(unsigned short, h);
}
__device__ inline unsigned int pack2bf(float a, float b) {
  return (unsigned int)f2bf(a) | ((unsigned int)f2bf(b) << 16);
}
__device__ inline float bf2f(unsigned short u) {
  return __bfloat162float(__builtin_bit_cast(__hip_bfloat16, u));
}
}

// lcP[c2*128 + k] = pack(bf16(lc[k][2*c2]), bf16(lc[k][2*c2+1]))  (64 KB)
__global__ __launch_bounds__(256) void prep_lcP(const float* __restrict__ lc,
                                                unsigned int* __restrict__ lcP) {
  for (int i = 0; i < 64; ++i) {
    int idx = threadIdx.x + 256 * (blockIdx.x * 64 + i);
    if (idx < 128 * 128) {
      int c2 = idx >> 7, k = idx & 127;
      lcP[idx] = pack2bf(lc[k * Cn + 2 * c2], lc[k * Cn + 2 * c2 + 1]);
    }
  }
}

// comb[b][k][p] (bf16) = sum_c lc[k][c] * x[b][c][p], via mfma_f32_16x16x32_bf16.
// A-operand = x (M=p), B-operand = lcP (N=k). D[m=p][n=k]: col=lane&15 (k),
// row=(lane>>4)*4+reg (p) [m89-verified layout]. Zero LDS, zero barriers.
// Block: 256 thr = 4 waves; block tile = 128p x 128k; wave owns 32p x 128k.
__global__ __launch_bounds__(256) void gemm_mfma(const float* __restrict__ x,
                                                 const unsigned int* __restrict__ lcP,
                                                 unsigned short* __restrict__ combh) {
  const int tid = threadIdx.x;
  const int wid = tid >> 6;
  const int lane = tid & 63;
  const int l15 = lane & 15, l4 = lane >> 4;
  const int b = blockIdx.x / 98;
  const int p0 = (blockIdx.x % 98) * 128 + wid * 32;  // wave p-base
  const float* xb = x + (size_t)b * Cn * Pn;

  f32x4 acc[8][2];  // [ksub][psub]
#pragma unroll
  for (int ks = 0; ks < 8; ++ks)
#pragma unroll
    for (int ps = 0; ps < 2; ++ps) acc[ks][ps] = (f32x4)(0.f);

#pragma unroll 2
  for (int s = 0; s < 8; ++s) {  // K-step: c = 32*s .. +31
    // A-frags from x: lane holds A[m=p][c=(l>>4)*8+j], j=0..7 (8 fp32 -> 4 bf16x2)
    unsigned int a[2][4];
#pragma unroll
    for (int ps = 0; ps < 2; ++ps) {
      const float* src = xb + (size_t)(32 * s + l4 * 8) * Pn + (p0 + ps * 16 + l15);
      float v[8];
#pragma unroll
      for (int j = 0; j < 8; ++j) v[j] = src[(size_t)j * Pn];
#pragma unroll
      for (int r = 0; r < 4; ++r) a[ps][r] = pack2bf(v[2 * r], v[2 * r + 1]);
    }
    // B-frags from lcP: lane holds B[c=(l>>4)*8+j][n=k], reg r = c-pair (l4*8+2r, +1)
#pragma unroll
    for (int ks = 0; ks < 8; ++ks) {
      unsigned int bf[4];
      const unsigned int* bp = lcP + (16 * s + l4 * 4) * 128 + ks * 16 + l15;
#pragma unroll
      for (int r = 0; r < 4; ++r) bf[r] = bp[r * 128];
      union { unsigned int u[4]; bf16x8 v; } bu;
      bu.u[0] = bf[0]; bu.u[1] = bf[1]; bu.u[2] = bf[2]; bu.u[3] = bf[3];
#pragma unroll
      for (int ps = 0; ps < 2; ++ps) {
        union { unsigned int u[4]; bf16x8 v; } au;
        au.u[0] = a[ps][0]; au.u[1] = a[ps][1]; au.u[2] = a[ps][2]; au.u[3] = a[ps][3];
        acc[ks][ps] = __builtin_amdgcn_mfma_f32_16x16x32_bf16(au.v, bu.v, acc[ks][ps], 0, 0, 0);
      }
    }
  }

  // Store: frag (ks,ps): lane -> k = ks*16 + l15, p = p0 + ps*16 + l4*4 + {0..3}
#pragma unroll
  for (int ks = 0; ks < 8; ++ks) {
    const size_t krow = ((size_t)b * Kn + ks * 16 + l15) * Pn;
#pragma unroll
    for (int ps = 0; ps < 2; ++ps) {
      const int p = p0 + ps * 16 + l4 * 4;
      uint2 st;
      st.x = pack2bf(acc[ks][ps][0], acc[ks][ps][1]);
      st.y = pack2bf(acc[ks][ps][2], acc[ks][ps][3]);
      *reinterpret_cast<uint2*>(combh + krow + p) = st;
    }
  }
}

// One thread per (k, p): bilinear gather from bf16 comb, reused weights across batch.
template <int FUSE>
__global__ __launch_bounds__(256) void sample_all(const unsigned short* __restrict__ comb,
                                                  const float* __restrict__ geo,
                                                  const float* __restrict__ boxp,
                                                  float* __restrict__ outF,
                                                  float* __restrict__ outW,
                                                  float* __restrict__ outB) {
  const int k = blockIdx.y;
  const int p = blockIdx.x * 256 + threadIdx.x;  // 49*256 == 12544
  const int h = p / Wn;
  const int w = p - h * Wn;
  const float xn = (2.f * w + 1.f) / (float)Wn - 1.f;
  const float yn = (2.f * h + 1.f) / (float)Hn - 1.f;

  const float* g = geo + k * 6;
  const float* t = boxp + k * 6;

  float ix = ((g[0] * xn + g[1] * yn + g[2] + 1.f) * Wn - 1.f) * 0.5f;
  float iy = ((g[3] * xn + g[4] * yn + g[5] + 1.f) * Hn - 1.f) * 0.5f;
  float x0f = floorf(ix), y0f = floorf(iy);
  float wx1 = ix - x0f, wx0 = 1.f - wx1;
  float wy1 = iy - y0f, wy0 = 1.f - wy1;
  float vx0 = (x0f >= 0.f && x0f <= (float)(Wn - 1)) ? 1.f : 0.f;
  float vx1 = (x0f + 1.f >= 0.f && x0f + 1.f <= (float)(Wn - 1)) ? 1.f : 0.f;
  float vy0 = (y0f >= 0.f && y0f <= (float)(Hn - 1)) ? 1.f : 0.f;
  float vy1 = (y0f + 1.f >= 0.f && y0f + 1.f <= (float)(Hn - 1)) ? 1.f : 0.f;
  int x0i = (int)fminf(fmaxf(x0f, 0.f), (float)(Wn - 1));
  int x1i = (int)fminf(fmaxf(x0f + 1.f, 0.f), (float)(Wn - 1));
  int y0i = (int)fminf(fmaxf(y0f, 0.f), (float)(Hn - 1));
  int y1i = (int)fminf(fmaxf(y0f + 1.f, 0.f), (float)(Hn - 1));
  float w00 = wx0 * wy0 * vx0 * vy0;
  float w01 = wx1 * wy0 * vx1 * vy0;
  float w10 = wx0 * wy1 * vx0 * vy1;
  float w11 = wx1 * wy1 * vx1 * vy1;
  int i00 = y0i * Wn + x0i, i01 = y0i * Wn + x1i;
  int i10 = y1i * Wn + x0i, i11 = y1i * Wn + x1i;

  float bix = ((t[0] * xn + t[1] * yn + t[2] + 1.f) * Wn - 1.f) * 0.5f;
  float biy = ((t[3] * xn + t[4] * yn + t[5] + 1.f) * Hn - 1.f) * 0.5f;
  float bx0 = floorf(bix), by0 = floorf(biy);
  float bwx1 = bix - bx0, bwx0 = 1.f - bwx1;
  float bwy1 = biy - by0, bwy0 = 1.f - bwy1;
  float bvx0 = (bx0 >= 0.f && bx0 <= (float)(Wn - 1)) ? 1.f : 0.f;
  float bvx1 = (bx0 + 1.f >= 0.f && bx0 + 1.f <= (float)(Wn - 1)) ? 1.f : 0.f;
  float bvy0 = (by0 >= 0.f && by0 <= (float)(Hn - 1)) ? 1.f : 0.f;
  float bvy1 = (by0 + 1.f >= 0.f && by0 + 1.f <= (float)(Hn - 1)) ? 1.f : 0.f;
  float bv = bwx0 * bwy0 * bvx0 * bvy0 + bwx1 * bwy0 * bvx1 * bvy0 +
             bwx0 * bwy1 * bvx0 * bvy1 + bwx1 * bwy1 * bvx1 * bvy1;

#pragma unroll
  for (int b = 0; b < Bn; ++b) {
    const unsigned short* cp = comb + ((size_t)b * Kn + k) * Pn;
    float v = w00 * bf2f(cp[i00]) + w01 * bf2f(cp[i01]) +
              w10 * bf2f(cp[i10]) + w11 * bf2f(cp[i11]);
    size_t o = ((size_t)b * Kn + k) * Pn + p;
    outW[o] = v;
    outB[o] = bv;
    if (FUSE) outF[o] = v * bv;
  }
}

// finalPred = warped * box (fallback when comb borrowed the outF region)
__global__ __launch_bounds__(256) void mul_fw(const float* __restrict__ w,
                                              const float* __restrict__ bx,
                                              float* __restrict__ f) {
  const long long n4 = NOUT / 4;
  for (long long i = blockIdx.x * 256LL + threadIdx.x; i < n4;
       i += (long long)gridDim.x * 256LL) {
    float4 a = reinterpret_cast<const float4*>(w)[i];
    float4 b = reinterpret_cast<const float4*>(bx)[i];
    reinterpret_cast<float4*>(f)[i] = make_float4(a.x * b.x, a.y * b.y, a.z * b.z, a.w * b.w);
  }
}

extern "C" void kernel_launch(void* const* d_in, const int* in_sizes, int n_in,
                              void* d_out, int out_size, void* d_ws, size_t ws_size,
                              hipStream_t stream) {
  (void)in_sizes; (void)n_in; (void)out_size;
  const float* x = (const float*)d_in[0];
  const float* lc = (const float*)d_in[1];
  const float* geo = (const float*)d_in[2];
  const float* boxp = (const float*)d_in[3];
  float* outF = (float*)d_out;
  float* outW = outF + NOUT;
  float* outB = outW + NOUT;

  // lcP (64 KB) lives at the start of outB: consumed by gemm, overwritten by sampler later.
  unsigned int* lcP = (unsigned int*)outB;

  const size_t comb_bytes = (size_t)NOUT * sizeof(unsigned short);  // 25.7 MB
  const bool use_ws = ws_size >= comb_bytes;
  unsigned short* combh = use_ws ? (unsigned short*)d_ws : (unsigned short*)outF;

  prep_lcP<<<1, 256, 0, stream>>>(lc, lcP);
  gemm_mfma<<<Bn * (Pn / 128), 256, 0, stream>>>(x, lcP, combh);
  if (use_ws) {
    sample_all<1><<<dim3(Pn / 256, Kn), 256, 0, stream>>>(combh, geo, boxp, outF, outW, outB);
  } else {
    sample_all<0><<<dim3(Pn / 256, Kn), 256, 0, stream>>>(combh, geo, boxp, outF, outW, outB);
    mul_fw<<<2048, 256, 0, stream>>>(outW, outB, outF);
  }
}

// Round 13
// 295.594 us; speedup vs baseline: 1.1306x; 1.0432x over previous
//
#include <hip/hip_runtime.h>
#include <hip/hip_bf16.h>

namespace {
constexpr int Bn = 8, Cn = 256, Kn = 128, Hn = 112, Wn = 112;
constexpr int Pn = Hn * Wn;                          // 12544 = 98*128 = 49*256
constexpr long long NOUT = (long long)Bn * Kn * Pn;  // 12845056 per output tensor

typedef __attribute__((ext_vector_type(8))) short bf16x8;
typedef __attribute__((ext_vector_type(4))) float f32x4;

__device__ inline unsigned short f2bf(float f) {
  __hip_bfloat16 h = __float2bfloat16(f);  // RNE
  return __builtin_bit_cast(unsigned short, h);
}
__device__ inline unsigned int pack2bf(float a, float b) {
  return (unsigned int)f2bf(a) | ((unsigned int)f2bf(b) << 16);
}
__device__ inline float bf2f(unsigned short u) {
  return __bfloat162float(__builtin_bit_cast(__hip_bfloat16, u));
}
}

// lcQ packed for vectorized B-frag loads: uint at
//   idx = ((((s*8+ks)*4+l4)*16)+l15)*4 + r   (s:c-step, ks:k-subtile, r:reg)
// holds pack(bf16(lc[k][2*c2]), bf16(lc[k][2*c2+1])), c2 = s*16+l4*4+r, k = ks*16+l15.
// One uint4 per lane per (s,ks). 64 KB total.
__global__ __launch_bounds__(256) void prep_lcQ(const float* __restrict__ lc,
                                                unsigned int* __restrict__ lcQ) {
  int idx = blockIdx.x * 256 + threadIdx.x;  // 64 blocks -> 16384
  int r = idx & 3;
  int l15 = (idx >> 2) & 15;
  int l4 = (idx >> 6) & 3;
  int ks = (idx >> 8) & 7;
  int s = idx >> 11;
  int c2 = s * 16 + l4 * 4 + r;
  int k = ks * 16 + l15;
  lcQ[idx] = pack2bf(lc[k * Cn + 2 * c2], lc[k * Cn + 2 * c2 + 1]);
}

// comb[b][k][p] (bf16) = sum_c lc[k][c] * x[b][c][p], via mfma_f32_16x16x32_bf16.
// A = x (M=p), B = lcQ (N=k). D: col(lane&15)=k, row((lane>>4)*4+reg)=p [m89].
// Zero LDS/barriers. 256 thr = 4 waves; block tile 128p x 128k; wave 32p x 128k.
__global__ __launch_bounds__(256) void gemm_mfma(const float* __restrict__ x,
                                                 const uint4* __restrict__ lcQ4,
                                                 unsigned short* __restrict__ combh) {
  const int tid = threadIdx.x;
  const int wid = tid >> 6;
  const int lane = tid & 63;
  const int l15 = lane & 15, l4 = lane >> 4;
  const int b = blockIdx.x / 98;
  const int p0 = (blockIdx.x % 98) * 128 + wid * 32;  // wave p-base
  const float* xb = x + (size_t)b * Cn * Pn;

  f32x4 acc[8][2];  // [ksub][psub]
#pragma unroll
  for (int ks = 0; ks < 8; ++ks)
#pragma unroll
    for (int ps = 0; ps < 2; ++ps) acc[ks][ps] = (f32x4)(0.f);

#pragma unroll 2
  for (int s = 0; s < 8; ++s) {  // K-step: c = 32*s .. +31
    // A-frags: lane holds A[m=p][c=(l>>4)*8+j], j=0..7 (8 fp32 -> 4 bf16x2)
    unsigned int a[2][4];
#pragma unroll
    for (int ps = 0; ps < 2; ++ps) {
      const float* src = xb + (size_t)(32 * s + l4 * 8) * Pn + (p0 + ps * 16 + l15);
      float v[8];
#pragma unroll
      for (int j = 0; j < 8; ++j) v[j] = src[(size_t)j * Pn];
#pragma unroll
      for (int r = 0; r < 4; ++r) a[ps][r] = pack2bf(v[2 * r], v[2 * r + 1]);
    }
    // B-frags: ONE uint4 per (s,ks) thanks to lcQ packing
#pragma unroll
    for (int ks = 0; ks < 8; ++ks) {
      uint4 bq = lcQ4[((s * 8 + ks) * 4 + l4) * 16 + l15];
      union { uint4 q; bf16x8 v; } bu;
      bu.q = bq;
#pragma unroll
      for (int ps = 0; ps < 2; ++ps) {
        union { unsigned int u[4]; bf16x8 v; } au;
        au.u[0] = a[ps][0]; au.u[1] = a[ps][1]; au.u[2] = a[ps][2]; au.u[3] = a[ps][3];
        acc[ks][ps] = __builtin_amdgcn_mfma_f32_16x16x32_bf16(au.v, bu.v, acc[ks][ps], 0, 0, 0);
      }
    }
  }

  // Store: frag (ks,ps): lane -> k = ks*16 + l15, p = p0 + ps*16 + l4*4 + {0..3}
#pragma unroll
  for (int ks = 0; ks < 8; ++ks) {
    const size_t krow = ((size_t)b * Kn + ks * 16 + l15) * Pn;
#pragma unroll
    for (int ps = 0; ps < 2; ++ps) {
      const int p = p0 + ps * 16 + l4 * 4;
      uint2 st;
      st.x = pack2bf(acc[ks][ps][0], acc[ks][ps][1]);
      st.y = pack2bf(acc[ks][ps][2], acc[ks][ps][3]);
      *reinterpret_cast<uint2*>(combh + krow + p) = st;
    }
  }
}

// One thread per (k, p): bilinear gather from bf16 comb, weights reused across batch.
// Outputs are streamed with non-temporal stores (never re-read in ws path).
template <int FUSE>
__global__ __launch_bounds__(256) void sample_all(const unsigned short* __restrict__ comb,
                                                  const float* __restrict__ geo,
                                                  const float* __restrict__ boxp,
                                                  float* __restrict__ outF,
                                                  float* __restrict__ outW,
                                                  float* __restrict__ outB) {
  const int k = blockIdx.y;
  const int p = blockIdx.x * 256 + threadIdx.x;  // 49*256 == 12544
  const int h = p / Wn;
  const int w = p - h * Wn;
  const float xn = (2.f * w + 1.f) / (float)Wn - 1.f;
  const float yn = (2.f * h + 1.f) / (float)Hn - 1.f;

  const float* g = geo + k * 6;
  const float* t = boxp + k * 6;

  float ix = ((g[0] * xn + g[1] * yn + g[2] + 1.f) * Wn - 1.f) * 0.5f;
  float iy = ((g[3] * xn + g[4] * yn + g[5] + 1.f) * Hn - 1.f) * 0.5f;
  float x0f = floorf(ix), y0f = floorf(iy);
  float wx1 = ix - x0f, wx0 = 1.f - wx1;
  float wy1 = iy - y0f, wy0 = 1.f - wy1;
  float vx0 = (x0f >= 0.f && x0f <= (float)(Wn - 1)) ? 1.f : 0.f;
  float vx1 = (x0f + 1.f >= 0.f && x0f + 1.f <= (float)(Wn - 1)) ? 1.f : 0.f;
  float vy0 = (y0f >= 0.f && y0f <= (float)(Hn - 1)) ? 1.f : 0.f;
  float vy1 = (y0f + 1.f >= 0.f && y0f + 1.f <= (float)(Hn - 1)) ? 1.f : 0.f;
  int x0i = (int)fminf(fmaxf(x0f, 0.f), (float)(Wn - 1));
  int x1i = (int)fminf(fmaxf(x0f + 1.f, 0.f), (float)(Wn - 1));
  int y0i = (int)fminf(fmaxf(y0f, 0.f), (float)(Hn - 1));
  int y1i = (int)fminf(fmaxf(y0f + 1.f, 0.f), (float)(Hn - 1));
  float w00 = wx0 * wy0 * vx0 * vy0;
  float w01 = wx1 * wy0 * vx1 * vy0;
  float w10 = wx0 * wy1 * vx0 * vy1;
  float w11 = wx1 * wy1 * vx1 * vy1;
  int i00 = y0i * Wn + x0i, i01 = y0i * Wn + x1i;
  int i10 = y1i * Wn + x0i, i11 = y1i * Wn + x1i;

  float bix = ((t[0] * xn + t[1] * yn + t[2] + 1.f) * Wn - 1.f) * 0.5f;
  float biy = ((t[3] * xn + t[4] * yn + t[5] + 1.f) * Hn - 1.f) * 0.5f;
  float bx0 = floorf(bix), by0 = floorf(biy);
  float bwx1 = bix - bx0, bwx0 = 1.f - bwx1;
  float bwy1 = biy - by0, bwy0 = 1.f - bwy1;
  float bvx0 = (bx0 >= 0.f && bx0 <= (float)(Wn - 1)) ? 1.f : 0.f;
  float bvx1 = (bx0 + 1.f >= 0.f && bx0 + 1.f <= (float)(Wn - 1)) ? 1.f : 0.f;
  float bvy0 = (by0 >= 0.f && by0 <= (float)(Hn - 1)) ? 1.f : 0.f;
  float bvy1 = (by0 + 1.f >= 0.f && by0 + 1.f <= (float)(Hn - 1)) ? 1.f : 0.f;
  float bv = bwx0 * bwy0 * bvx0 * bvy0 + bwx1 * bwy0 * bvx1 * bvy0 +
             bwx0 * bwy1 * bvx0 * bvy1 + bwx1 * bwy1 * bvx1 * bvy1;

#pragma unroll
  for (int b = 0; b < Bn; ++b) {
    const unsigned short* cp = comb + ((size_t)b * Kn + k) * Pn;
    float v = w00 * bf2f(cp[i00]) + w01 * bf2f(cp[i01]) +
              w10 * bf2f(cp[i10]) + w11 * bf2f(cp[i11]);
    size_t o = ((size_t)b * Kn + k) * Pn + p;
    __builtin_nontemporal_store(v, &outW[o]);
    __builtin_nontemporal_store(bv, &outB[o]);
    if (FUSE) __builtin_nontemporal_store(v * bv, &outF[o]);
  }
}

// finalPred = warped * box (fallback when comb borrowed the outF region)
// NT store must use a clang ext_vector type (HIP float4 is a class -> rejected).
__global__ __launch_bounds__(256) void mul_fw(const float* __restrict__ w,
                                              const float* __restrict__ bx,
                                              float* __restrict__ f) {
  const long long n4 = NOUT / 4;
  const f32x4* w4 = reinterpret_cast<const f32x4*>(w);
  const f32x4* b4 = reinterpret_cast<const f32x4*>(bx);
  f32x4* f4 = reinterpret_cast<f32x4*>(f);
  for (long long i = blockIdx.x * 256LL + threadIdx.x; i < n4;
       i += (long long)gridDim.x * 256LL) {
    f32x4 r = w4[i] * b4[i];
    __builtin_nontemporal_store(r, &f4[i]);
  }
}

extern "C" void kernel_launch(void* const* d_in, const int* in_sizes, int n_in,
                              void* d_out, int out_size, void* d_ws, size_t ws_size,
                              hipStream_t stream) {
  (void)in_sizes; (void)n_in; (void)out_size;
  const float* x = (const float*)d_in[0];
  const float* lc = (const float*)d_in[1];
  const float* geo = (const float*)d_in[2];
  const float* boxp = (const float*)d_in[3];
  float* outF = (float*)d_out;
  float* outW = outF + NOUT;
  float* outB = outW + NOUT;

  // lcQ (64 KB) at the start of outB: consumed by gemm, overwritten by sampler later.
  unsigned int* lcQ = (unsigned int*)outB;

  const size_t comb_bytes = (size_t)NOUT * sizeof(unsigned short);  // 25.7 MB
  const bool use_ws = ws_size >= comb_bytes;
  unsigned short* combh = use_ws ? (unsigned short*)d_ws : (unsigned short*)outF;

  prep_lcQ<<<64, 256, 0, stream>>>(lc, lcQ);
  gemm_mfma<<<Bn * (Pn / 128), 256, 0, stream>>>(x, (const uint4*)lcQ, combh);
  if (use_ws) {
    sample_all<1><<<dim3(Pn / 256, Kn), 256, 0, stream>>>(combh, geo, boxp, outF, outW, outB);
  } else {
    sample_all<0><<<dim3(Pn / 256, Kn), 256, 0, stream>>>(combh, geo, boxp, outF, outW, outB);
    mul_fw<<<2048, 256, 0, stream>>>(outW, outB, outF);
  }
}

// Round 14
// 278.591 us; speedup vs baseline: 1.1996x; 1.0610x over previous
//
#include <hip/hip_runtime.h>
#include <hip/hip_bf16.h>

namespace {
constexpr int Bn = 8, Cn = 256, Kn = 128, Hn = 112, Wn = 112;
constexpr int Pn = Hn * Wn;                          // 12544 = 196*64 = 49*256
constexpr long long NOUT = (long long)Bn * Kn * Pn;  // 12845056 per output tensor

typedef __attribute__((ext_vector_type(8))) short bf16x8;
typedef __attribute__((ext_vector_type(4))) float f32x4;

__device__ inline unsigned short f2bf(float f) {
  __hip_bfloat16 h = __float2bfloat16(f);  // RNE
  return __builtin_bit_cast(unsigned short, h);
}
__device__ inline unsigned int pack2bf(float a, float b) {
  return (unsigned int)f2bf(a) | ((unsigned int)f2bf(b) << 16);
}
__device__ inline float bf2f(unsigned short u) {
  return __bfloat162float(__builtin_bit_cast(__hip_bfloat16, u));
}
}

// lcQ packed for vectorized B-frag loads: uint at
//   idx = ((((s*8+ks)*4+l4)*16)+l15)*4 + r
// holds pack(bf16(lc[k][2*c2]), bf16(lc[k][2*c2+1])), c2 = s*16+l4*4+r, k = ks*16+l15.
__global__ __launch_bounds__(256) void prep_lcQ(const float* __restrict__ lc,
                                                unsigned int* __restrict__ lcQ) {
  int idx = blockIdx.x * 256 + threadIdx.x;  // 64 blocks -> 16384
  int r = idx & 3;
  int l15 = (idx >> 2) & 15;
  int l4 = (idx >> 6) & 3;
  int ks = (idx >> 8) & 7;
  int s = idx >> 11;
  int c2 = s * 16 + l4 * 4 + r;
  int k = ks * 16 + l15;
  lcQ[idx] = pack2bf(lc[k * Cn + 2 * c2], lc[k * Cn + 2 * c2 + 1]);
}

// comb[b][k][p] (bf16) = sum_c lc[k][c] * x[b][c][p], via mfma_f32_16x16x32_bf16.
// 64p x 128k block tile, 4 waves (16p x 128k each) -> 1568 blocks, ~5-6 waves/SIMD
// for latency hiding (R13: 3/SIMD was latency-bound). acc = 8 frags = 32 VGPR.
__global__ __launch_bounds__(256) void gemm_mfma(const float* __restrict__ x,
                                                 const uint4* __restrict__ lcQ4,
                                                 unsigned short* __restrict__ combh) {
  const int tid = threadIdx.x;
  const int wid = tid >> 6;
  const int lane = tid & 63;
  const int l15 = lane & 15, l4 = lane >> 4;
  const int b = blockIdx.x / 196;
  const int p0 = (blockIdx.x % 196) * 64 + wid * 16;  // wave p-base (16 p)
  const float* xb = x + (size_t)b * Cn * Pn;

  f32x4 acc[8];
#pragma unroll
  for (int ks = 0; ks < 8; ++ks) acc[ks] = (f32x4)(0.f);

#pragma unroll 2
  for (int s = 0; s < 8; ++s) {  // K-step: c = 32*s .. +31
    // A-frag: lane holds A[m=p0+l15][c = 32s + l4*8 + j], j=0..7
    const float* src = xb + (size_t)(32 * s + l4 * 8) * Pn + (p0 + l15);
    float v[8];
#pragma unroll
    for (int j = 0; j < 8; ++j) v[j] = src[(size_t)j * Pn];
    union { unsigned int u[4]; bf16x8 vv; } au;
#pragma unroll
    for (int r = 0; r < 4; ++r) au.u[r] = pack2bf(v[2 * r], v[2 * r + 1]);
    // B-frags: one uint4 per ks
#pragma unroll
    for (int ks = 0; ks < 8; ++ks) {
      union { uint4 q; bf16x8 vv; } bu;
      bu.q = lcQ4[((s * 8 + ks) * 4 + l4) * 16 + l15];
      acc[ks] = __builtin_amdgcn_mfma_f32_16x16x32_bf16(au.vv, bu.vv, acc[ks], 0, 0, 0);
    }
  }

  // D: col(l15)=k, row(l4*4+reg)=p. Store uint2 (4 bf16) per frag.
#pragma unroll
  for (int ks = 0; ks < 8; ++ks) {
    const size_t o = ((size_t)b * Kn + ks * 16 + l15) * Pn + p0 + l4 * 4;
    uint2 st;
    st.x = pack2bf(acc[ks][0], acc[ks][1]);
    st.y = pack2bf(acc[ks][2], acc[ks][3]);
    *reinterpret_cast<uint2*>(combh + o) = st;
  }
}

// One block per (b,k): stage the full 112x112 bf16 image in LDS (coalesced),
// then bilinear-gather from LDS. Kills the diagonal-gather line-splitting
// (global: 64 lanes -> 64 cache lines per gather; LDS: ~2-4 way banks, ~free).
// Each block reads/writes only its own slab -> safe even when comb aliases outF.
__global__ __launch_bounds__(256) void sample_lds(const unsigned short* __restrict__ comb,
                                                  const float* __restrict__ geo,
                                                  const float* __restrict__ boxp,
                                                  float* __restrict__ outF,
                                                  float* __restrict__ outW,
                                                  float* __restrict__ outB) {
  __shared__ __align__(16) unsigned short img[Pn];  // 25088 B
  const int bx = blockIdx.x;       // 0..1023 = b*128 + k
  const int k = bx & 127;
  const int tid = threadIdx.x;

  // stage: 12544 ushort = 1568 uint4
  {
    const uint4* src = reinterpret_cast<const uint4*>(comb + (size_t)bx * Pn);
    uint4* dst = reinterpret_cast<uint4*>(img);
    for (int i = tid; i < Pn / 8; i += 256) dst[i] = src[i];
  }
  __syncthreads();

  const float* g = geo + k * 6;
  const float* t = boxp + k * 6;
  const float g0 = g[0], g1 = g[1], g2 = g[2], g3 = g[3], g4 = g[4], g5 = g[5];
  const float t0 = t[0], t1 = t[1], t2 = t[2], t3 = t[3], t4 = t[4], t5 = t[5];
  const size_t obase = (size_t)bx * Pn;

  for (int pp = tid; pp < Pn; pp += 256) {
    const int h = pp / Wn;
    const int w = pp - h * Wn;
    const float xn = (2.f * w + 1.f) / (float)Wn - 1.f;
    const float yn = (2.f * h + 1.f) / (float)Hn - 1.f;

    float ix = ((g0 * xn + g1 * yn + g2 + 1.f) * Wn - 1.f) * 0.5f;
    float iy = ((g3 * xn + g4 * yn + g5 + 1.f) * Hn - 1.f) * 0.5f;
    float x0f = floorf(ix), y0f = floorf(iy);
    float wx1 = ix - x0f, wx0 = 1.f - wx1;
    float wy1 = iy - y0f, wy0 = 1.f - wy1;
    float vx0 = (x0f >= 0.f && x0f <= (float)(Wn - 1)) ? 1.f : 0.f;
    float vx1 = (x0f + 1.f >= 0.f && x0f + 1.f <= (float)(Wn - 1)) ? 1.f : 0.f;
    float vy0 = (y0f >= 0.f && y0f <= (float)(Hn - 1)) ? 1.f : 0.f;
    float vy1 = (y0f + 1.f >= 0.f && y0f + 1.f <= (float)(Hn - 1)) ? 1.f : 0.f;
    int x0i = (int)fminf(fmaxf(x0f, 0.f), (float)(Wn - 1));
    int x1i = (int)fminf(fmaxf(x0f + 1.f, 0.f), (float)(Wn - 1));
    int y0i = (int)fminf(fmaxf(y0f, 0.f), (float)(Hn - 1));
    int y1i = (int)fminf(fmaxf(y0f + 1.f, 0.f), (float)(Hn - 1));
    float w00 = wx0 * wy0 * vx0 * vy0;
    float w01 = wx1 * wy0 * vx1 * vy0;
    float w10 = wx0 * wy1 * vx0 * vy1;
    float w11 = wx1 * wy1 * vx1 * vy1;
    int i00 = y0i * Wn + x0i, i01 = y0i * Wn + x1i;
    int i10 = y1i * Wn + x0i, i11 = y1i * Wn + x1i;

    float bix = ((t0 * xn + t1 * yn + t2 + 1.f) * Wn - 1.f) * 0.5f;
    float biy = ((t3 * xn + t4 * yn + t5 + 1.f) * Hn - 1.f) * 0.5f;
    float bx0 = floorf(bix), by0 = floorf(biy);
    float bwx1 = bix - bx0, bwx0 = 1.f - bwx1;
    float bwy1 = biy - by0, bwy0 = 1.f - bwy1;
    float bvx0 = (bx0 >= 0.f && bx0 <= (float)(Wn - 1)) ? 1.f : 0.f;
    float bvx1 = (bx0 + 1.f >= 0.f && bx0 + 1.f <= (float)(Wn - 1)) ? 1.f : 0.f;
    float bvy0 = (by0 >= 0.f && by0 <= (float)(Hn - 1)) ? 1.f : 0.f;
    float bvy1 = (by0 + 1.f >= 0.f && by0 + 1.f <= (float)(Hn - 1)) ? 1.f : 0.f;
    float bv = bwx0 * bwy0 * bvx0 * bvy0 + bwx1 * bwy0 * bvx1 * bvy0 +
               bwx0 * bwy1 * bvx0 * bvy1 + bwx1 * bwy1 * bvx1 * bvy1;

    float v = w00 * bf2f(img[i00]) + w01 * bf2f(img[i01]) +
              w10 * bf2f(img[i10]) + w11 * bf2f(img[i11]);
    const size_t o = obase + pp;
    __builtin_nontemporal_store(v, &outW[o]);
    __builtin_nontemporal_store(bv, &outB[o]);
    __builtin_nontemporal_store(v * bv, &outF[o]);
  }
}

extern "C" void kernel_launch(void* const* d_in, const int* in_sizes, int n_in,
                              void* d_out, int out_size, void* d_ws, size_t ws_size,
                              hipStream_t stream) {
  (void)in_sizes; (void)n_in; (void)out_size;
  const float* x = (const float*)d_in[0];
  const float* lc = (const float*)d_in[1];
  const float* geo = (const float*)d_in[2];
  const float* boxp = (const float*)d_in[3];
  float* outF = (float*)d_out;
  float* outW = outF + NOUT;
  float* outB = outW + NOUT;

  // lcQ (64 KB) at the start of outB: consumed by gemm before sampler overwrites.
  unsigned int* lcQ = (unsigned int*)outB;

  const size_t comb_bytes = (size_t)NOUT * sizeof(unsigned short);  // 25.7 MB
  const bool use_ws = ws_size >= comb_bytes;
  // Fallback: borrow outF. Safe: sampler block (b,k) reads only its own slab
  // into LDS before writing that same slab.
  unsigned short* combh = use_ws ? (unsigned short*)d_ws : (unsigned short*)outF;

  prep_lcQ<<<64, 256, 0, stream>>>(lc, lcQ);
  gemm_mfma<<<Bn * (Pn / 64), 256, 0, stream>>>(x, (const uint4*)lcQ, combh);
  sample_lds<<<Bn * Kn, 256, 0, stream>>>(combh, geo, boxp, outF, outW, outB);
}

// Round 15
// 274.659 us; speedup vs baseline: 1.2168x; 1.0143x over previous
//
#include <hip/hip_runtime.h>
#include <hip/hip_bf16.h>

namespace {
constexpr int Bn = 8, Cn = 256, Kn = 128, Hn = 112, Wn = 112;
constexpr int Pn = Hn * Wn;                          // 12544 = 196*64 = 49*256
constexpr long long NOUT = (long long)Bn * Kn * Pn;  // 12845056 per output tensor

typedef __attribute__((ext_vector_type(8))) short bf16x8;
typedef __attribute__((ext_vector_type(4))) float f32x4;

__device__ inline unsigned short f2bf(float f) {
  __hip_bfloat16 h = __float2bfloat16(f);  // RNE
  return __builtin_bit_cast(unsigned short, h);
}
__device__ inline unsigned int pack2bf(float a, float b) {
  return (unsigned int)f2bf(a) | ((unsigned int)f2bf(b) << 16);
}
__device__ inline float bf2f(unsigned short u) {
  return __bfloat162float(__builtin_bit_cast(__hip_bfloat16, u));
}
}

// lcQ packed for vectorized B-frag loads: uint at
//   idx = ((((s*8+ks)*4+l4)*16)+l15)*4 + r
// holds pack(bf16(lc[k][2*c2]), bf16(lc[k][2*c2+1])), c2 = s*16+l4*4+r, k = ks*16+l15.
__global__ __launch_bounds__(256) void prep_lcQ(const float* __restrict__ lc,
                                                unsigned int* __restrict__ lcQ) {
  int idx = blockIdx.x * 256 + threadIdx.x;  // 64 blocks -> 16384
  int r = idx & 3;
  int l15 = (idx >> 2) & 15;
  int l4 = (idx >> 6) & 3;
  int ks = (idx >> 8) & 7;
  int s = idx >> 11;
  int c2 = s * 16 + l4 * 4 + r;
  int k = ks * 16 + l15;
  lcQ[idx] = pack2bf(lc[k * Cn + 2 * c2], lc[k * Cn + 2 * c2 + 1]);
}

// comb[b][k][p] (bf16) = sum_c lc[k][c] * x[b][c][p], mfma_f32_16x16x32_bf16.
// R14 issue: 64 scalar stride-Pn A-loads/wave -> latency-bound at ~6 waves/SIMD.
// Fix: LDS-stage x tile [32c][64p] fp32 (8KB/step), double-buffered, async-split
// staging (issue loads -> compute -> ds_write -> barrier). A-frags then come from
// LDS (4-way bank alias = 1.58x, acceptable); B (lcQ) stays global (L1/L2-hot).
__global__ __launch_bounds__(256) void gemm_mfma(const float* __restrict__ x,
                                                 const uint4* __restrict__ lcQ4,
                                                 unsigned short* __restrict__ combh) {
  __shared__ __align__(16) float xs[2][32][64];  // 16 KB double-buffer
  const int tid = threadIdx.x;
  const int wid = tid >> 6;
  const int lane = tid & 63;
  const int l15 = lane & 15, l4 = lane >> 4;
  const int b = blockIdx.x / 196;
  const int p0 = (blockIdx.x % 196) * 64;  // block p-base (64 p)
  const float* xb = x + (size_t)b * Cn * Pn + p0;

  // staging map: 512 float4 per step; thread t takes fidx = i*256+t (i=0,1):
  // row = fidx/16 (c-row), col4 = fidx%16 (16B chunk within the 64-float row).
  const int srow0 = tid >> 4;          // i=0: rows 0..15
  const int scol = (tid & 15) * 4;     // float offset
  const int srow1 = srow0 + 16;       // i=1: rows 16..31

  f32x4 acc[8];
#pragma unroll
  for (int ks = 0; ks < 8; ++ks) acc[ks] = (f32x4)(0.f);

  // prologue: stage step 0 into buf 0
  {
    float4 v0 = *reinterpret_cast<const float4*>(xb + (size_t)srow0 * Pn + scol);
    float4 v1 = *reinterpret_cast<const float4*>(xb + (size_t)srow1 * Pn + scol);
    *reinterpret_cast<float4*>(&xs[0][srow0][scol]) = v0;
    *reinterpret_cast<float4*>(&xs[0][srow1][scol]) = v1;
  }
  __syncthreads();

  for (int s = 0; s < 8; ++s) {
    const int cur = s & 1;
    // T14 async-split: issue next step's global loads BEFORE compute
    float4 n0, n1;
    if (s < 7) {
      const float* g = xb + (size_t)(32 * (s + 1)) * Pn;
      n0 = *reinterpret_cast<const float4*>(g + (size_t)srow0 * Pn + scol);
      n1 = *reinterpret_cast<const float4*>(g + (size_t)srow1 * Pn + scol);
    }

    // compute: A-frag from LDS: x[c=l4*8+j][p=wid*16+l15]
    float v[8];
#pragma unroll
    for (int j = 0; j < 8; ++j) v[j] = xs[cur][l4 * 8 + j][wid * 16 + l15];
    union { unsigned int u[4]; bf16x8 vv; } au;
#pragma unroll
    for (int r = 0; r < 4; ++r) au.u[r] = pack2bf(v[2 * r], v[2 * r + 1]);
#pragma unroll
    for (int ks = 0; ks < 8; ++ks) {
      union { uint4 q; bf16x8 vv; } bu;
      bu.q = lcQ4[((s * 8 + ks) * 4 + l4) * 16 + l15];
      acc[ks] = __builtin_amdgcn_mfma_f32_16x16x32_bf16(au.vv, bu.vv, acc[ks], 0, 0, 0);
    }

    // write the prefetched tile late (HBM latency hidden under MFMAs)
    if (s < 7) {
      *reinterpret_cast<float4*>(&xs[cur ^ 1][srow0][scol]) = n0;
      *reinterpret_cast<float4*>(&xs[cur ^ 1][srow1][scol]) = n1;
    }
    __syncthreads();
  }

  // D: col(l15)=k, row(l4*4+reg)=p. per-wave tile 16p x 128k.
#pragma unroll
  for (int ks = 0; ks < 8; ++ks) {
    const size_t o = ((size_t)b * Kn + ks * 16 + l15) * Pn + p0 + wid * 16 + l4 * 4;
    uint2 st;
    st.x = pack2bf(acc[ks][0], acc[ks][1]);
    st.y = pack2bf(acc[ks][2], acc[ks][3]);
    *reinterpret_cast<uint2*>(combh + o) = st;
  }
}

// One block per (b,k): stage full 112x112 bf16 image in LDS, gather from LDS.
__global__ __launch_bounds__(256) void sample_lds(const unsigned short* __restrict__ comb,
                                                  const float* __restrict__ geo,
                                                  const float* __restrict__ boxp,
                                                  float* __restrict__ outF,
                                                  float* __restrict__ outW,
                                                  float* __restrict__ outB) {
  __shared__ __align__(16) unsigned short img[Pn];  // 25088 B
  const int bx = blockIdx.x;  // b*128 + k
  const int k = bx & 127;
  const int tid = threadIdx.x;

  {
    const uint4* src = reinterpret_cast<const uint4*>(comb + (size_t)bx * Pn);
    uint4* dst = reinterpret_cast<uint4*>(img);
    for (int i = tid; i < Pn / 8; i += 256) dst[i] = src[i];
  }
  __syncthreads();

  const float* g = geo + k * 6;
  const float* t = boxp + k * 6;
  const float g0 = g[0], g1 = g[1], g2 = g[2], g3 = g[3], g4 = g[4], g5 = g[5];
  const float t0 = t[0], t1 = t[1], t2 = t[2], t3 = t[3], t4 = t[4], t5 = t[5];
  const size_t obase = (size_t)bx * Pn;

  for (int pp = tid; pp < Pn; pp += 256) {
    const int h = pp / Wn;
    const int w = pp - h * Wn;
    const float xn = (2.f * w + 1.f) / (float)Wn - 1.f;
    const float yn = (2.f * h + 1.f) / (float)Hn - 1.f;

    float ix = ((g0 * xn + g1 * yn + g2 + 1.f) * Wn - 1.f) * 0.5f;
    float iy = ((g3 * xn + g4 * yn + g5 + 1.f) * Hn - 1.f) * 0.5f;
    float x0f = floorf(ix), y0f = floorf(iy);
    float wx1 = ix - x0f, wx0 = 1.f - wx1;
    float wy1 = iy - y0f, wy0 = 1.f - wy1;
    float vx0 = (x0f >= 0.f && x0f <= (float)(Wn - 1)) ? 1.f : 0.f;
    float vx1 = (x0f + 1.f >= 0.f && x0f + 1.f <= (float)(Wn - 1)) ? 1.f : 0.f;
    float vy0 = (y0f >= 0.f && y0f <= (float)(Hn - 1)) ? 1.f : 0.f;
    float vy1 = (y0f + 1.f >= 0.f && y0f + 1.f <= (float)(Hn - 1)) ? 1.f : 0.f;
    int x0i = (int)fminf(fmaxf(x0f, 0.f), (float)(Wn - 1));
    int x1i = (int)fminf(fmaxf(x0f + 1.f, 0.f), (float)(Wn - 1));
    int y0i = (int)fminf(fmaxf(y0f, 0.f), (float)(Hn - 1));
    int y1i = (int)fminf(fmaxf(y0f + 1.f, 0.f), (float)(Hn - 1));
    float w00 = wx0 * wy0 * vx0 * vy0;
    float w01 = wx1 * wy0 * vx1 * vy0;
    float w10 = wx0 * wy1 * vx0 * vy1;
    float w11 = wx1 * wy1 * vx1 * vy1;
    int i00 = y0i * Wn + x0i, i01 = y0i * Wn + x1i;
    int i10 = y1i * Wn + x0i, i11 = y1i * Wn + x1i;

    float bix = ((t0 * xn + t1 * yn + t2 + 1.f) * Wn - 1.f) * 0.5f;
    float biy = ((t3 * xn + t4 * yn + t5 + 1.f) * Hn - 1.f) * 0.5f;
    float bx0 = floorf(bix), by0 = floorf(biy);
    float bwx1 = bix - bx0, bwx0 = 1.f - bwx1;
    float bwy1 = biy - by0, bwy0 = 1.f - bwy1;
    float bvx0 = (bx0 >= 0.f && bx0 <= (float)(Wn - 1)) ? 1.f : 0.f;
    float bvx1 = (bx0 + 1.f >= 0.f && bx0 + 1.f <= (float)(Wn - 1)) ? 1.f : 0.f;
    float bvy0 = (by0 >= 0.f && by0 <= (float)(Hn - 1)) ? 1.f : 0.f;
    float bvy1 = (by0 + 1.f >= 0.f && by0 + 1.f <= (float)(Hn - 1)) ? 1.f : 0.f;
    float bv = bwx0 * bwy0 * bvx0 * bvy0 + bwx1 * bwy0 * bvx1 * bvy0 +
               bwx0 * bwy1 * bvx0 * bvy1 + bwx1 * bwy1 * bvx1 * bvy1;

    float v = w00 * bf2f(img[i00]) + w01 * bf2f(img[i01]) +
              w10 * bf2f(img[i10]) + w11 * bf2f(img[i11]);
    const size_t o = obase + pp;
    __builtin_nontemporal_store(v, &outW[o]);
    __builtin_nontemporal_store(bv, &outB[o]);
    __builtin_nontemporal_store(v * bv, &outF[o]);
  }
}

extern "C" void kernel_launch(void* const* d_in, const int* in_sizes, int n_in,
                              void* d_out, int out_size, void* d_ws, size_t ws_size,
                              hipStream_t stream) {
  (void)in_sizes; (void)n_in; (void)out_size;
  const float* x = (const float*)d_in[0];
  const float* lc = (const float*)d_in[1];
  const float* geo = (const float*)d_in[2];
  const float* boxp = (const float*)d_in[3];
  float* outF = (float*)d_out;
  float* outW = outF + NOUT;
  float* outB = outW + NOUT;

  unsigned int* lcQ = (unsigned int*)outB;  // consumed by gemm before sampler writes

  const size_t comb_bytes = (size_t)NOUT * sizeof(unsigned short);  // 25.7 MB
  const bool use_ws = ws_size >= comb_bytes;
  unsigned short* combh = use_ws ? (unsigned short*)d_ws : (unsigned short*)outF;

  prep_lcQ<<<64, 256, 0, stream>>>(lc, lcQ);
  gemm_mfma<<<Bn * (Pn / 64), 256, 0, stream>>>(x, (const uint4*)lcQ, combh);
  sample_lds<<<Bn * Kn, 256, 0, stream>>>(combh, geo, boxp, outF, outW, outB);
}